// Round 1
// baseline (556.381 us; speedup 1.0000x reference)
//
#include <hip/hip_runtime.h>
#include <math.h>

#define N_TOK 32768
#define IN_DIM 1024
#define HID 256
#define NE 64

// Fused gating network:
//   phase A: H[64tok x 256hid] = relu(X W1^T + b1), K=1024 staged in 32-chunks
//   phase B: logits[64 x 64] = H W2^T + b2, H handed off through LDS (no HBM)
//   epilogue: per-token top-2 (ties -> lower index) + 2-way softmax
//
// All LDS tiles are stored [k][col] with an XOR swizzle on the float4-group of
// col, keyed by (k>>2)&7 (or &15 for Hs). This makes BOTH the transpose
// staging writes and the strided fragment reads conflict-free:
//   - reads: lane l reads group (g ^ s); within any 8-lane phase the groups
//     {0..7}^s are a permutation of {0..7} -> 8 distinct 16B slots = 32 banks.
//   - writes: lanes sharing a column differ in kq; kq>>2 enters the XOR so
//     their columns land in distinct bank groups.
union SMem {
    struct { float Xs[32][64]; float Ws[32][256]; } a;   // 8K + 32K
    struct { float Hs[128][64]; float W2s[32][64]; } b;  // 32K + 8K
    float Ls[64][67];                                    // 17K (pad 67: bank spread)
};

__global__ __launch_bounds__(256, 2)
void moe_gate_fused(const float* __restrict__ x,  const float* __restrict__ w1,
                    const float* __restrict__ b1, const float* __restrict__ w2,
                    const float* __restrict__ b2, float* __restrict__ out)
{
    __shared__ SMem sm;

    const int tid = threadIdx.x;
    const int t0  = blockIdx.x * 64;
    const int tg  = tid >> 5;       // 0..7  -> tokens tg*8 .. tg*8+7
    const int hg  = tid & 31;       // 0..31 -> hiddens {hg*4..+3, 128+hg*4..+3}

    float acc[8][8];
    #pragma unroll
    for (int i = 0; i < 8; ++i)
        #pragma unroll
        for (int j = 0; j < 8; ++j) acc[i][j] = 0.f;

    // ---------------- phase A: H = relu(X @ W1^T + b1) ----------------
    // register double-buffer for global->LDS staging
    float4 px[2], pw[8];
    #pragma unroll
    for (int r = 0; r < 2; ++r) {
        int slot = tid + 256 * r;
        int t = slot >> 3, kq = (slot & 7) * 4;
        px[r] = *(const float4*)(x + (size_t)(t0 + t) * IN_DIM + kq);
    }
    #pragma unroll
    for (int r = 0; r < 8; ++r) {
        int slot = tid + 256 * r;
        int hh = slot >> 3, kq = (slot & 7) * 4;
        pw[r] = *(const float4*)(w1 + (size_t)hh * IN_DIM + kq);
    }

    #pragma unroll 1
    for (int c = 0; c < 32; ++c) {
        // staged regs -> LDS (swizzled transpose, conflict-free)
        #pragma unroll
        for (int r = 0; r < 2; ++r) {
            int slot = tid + 256 * r;
            int t = slot >> 3, kq = (slot & 7) * 4;
            int col = (((t >> 2) ^ (kq >> 2)) << 2) | (t & 3);
            sm.a.Xs[kq + 0][col] = px[r].x;
            sm.a.Xs[kq + 1][col] = px[r].y;
            sm.a.Xs[kq + 2][col] = px[r].z;
            sm.a.Xs[kq + 3][col] = px[r].w;
        }
        #pragma unroll
        for (int r = 0; r < 8; ++r) {
            int slot = tid + 256 * r;
            int hh = slot >> 3, kq = (slot & 7) * 4;
            int col = (((hh >> 2) ^ (kq >> 2)) << 2) | (hh & 3);
            sm.a.Ws[kq + 0][col] = pw[r].x;
            sm.a.Ws[kq + 1][col] = pw[r].y;
            sm.a.Ws[kq + 2][col] = pw[r].z;
            sm.a.Ws[kq + 3][col] = pw[r].w;
        }
        __syncthreads();

        // prefetch next chunk while we compute this one
        if (c < 31) {
            int k0 = (c + 1) * 32;
            #pragma unroll
            for (int r = 0; r < 2; ++r) {
                int slot = tid + 256 * r;
                int t = slot >> 3, kq = (slot & 7) * 4;
                px[r] = *(const float4*)(x + (size_t)(t0 + t) * IN_DIM + k0 + kq);
            }
            #pragma unroll
            for (int r = 0; r < 8; ++r) {
                int slot = tid + 256 * r;
                int hh = slot >> 3, kq = (slot & 7) * 4;
                pw[r] = *(const float4*)(w1 + (size_t)hh * IN_DIM + k0 + kq);
            }
        }

        // inner product: sx = k>>2 constant per m-group -> bases hoisted,
        // ds_read offsets become immediates
        #pragma unroll
        for (int m = 0; m < 8; ++m) {
            const float* xb0 = &sm.a.Xs[0][(((tg * 2)     ^ m) << 2)];
            const float* xb1 = &sm.a.Xs[0][(((tg * 2 + 1) ^ m) << 2)];
            const float* wb0 = &sm.a.Ws[0][(( hg ^ m)        << 2)];
            const float* wb1 = &sm.a.Ws[0][((((hg ^ m) + 32)) << 2)];
            #pragma unroll
            for (int kk = 0; kk < 4; ++kk) {
                int k = m * 4 + kk;
                float4 xv0 = *(const float4*)(xb0 + k * 64);
                float4 xv1 = *(const float4*)(xb1 + k * 64);
                float4 wv0 = *(const float4*)(wb0 + k * 256);
                float4 wv1 = *(const float4*)(wb1 + k * 256);
                float xv[8] = {xv0.x, xv0.y, xv0.z, xv0.w, xv1.x, xv1.y, xv1.z, xv1.w};
                float wv[8] = {wv0.x, wv0.y, wv0.z, wv0.w, wv1.x, wv1.y, wv1.z, wv1.w};
                #pragma unroll
                for (int i = 0; i < 8; ++i)
                    #pragma unroll
                    for (int j = 0; j < 8; ++j)
                        acc[i][j] = fmaf(xv[i], wv[j], acc[i][j]);
            }
        }
        __syncthreads();
    }

    // bias + relu (acc[i][j]: j 0..3 -> h=hg*4+j, j 4..7 -> h=128+hg*4+(j-4))
    {
        float4 bb0 = *(const float4*)(b1 + hg * 4);
        float4 bb1 = *(const float4*)(b1 + 128 + hg * 4);
        float bias1[8] = {bb0.x, bb0.y, bb0.z, bb0.w, bb1.x, bb1.y, bb1.z, bb1.w};
        #pragma unroll
        for (int i = 0; i < 8; ++i)
            #pragma unroll
            for (int j = 0; j < 8; ++j)
                acc[i][j] = fmaxf(acc[i][j] + bias1[j], 0.f);
    }

    // ---------------- phase B: logits = H @ W2^T + b2 ----------------
    const int ta = tid >> 4;   // 0..15 -> tokens  ta*4 .. ta*4+3
    const int eb = tid & 15;   // 0..15 -> experts eb*4 .. eb*4+3

    float acc2[4][4];
    #pragma unroll
    for (int i = 0; i < 4; ++i)
        #pragma unroll
        for (int j = 0; j < 4; ++j) acc2[i][j] = 0.f;

    #pragma unroll            // p MUST be compile-time (static acc indexing)
    for (int p = 0; p < 2; ++p) {
        // hand H half-slice to LDS: Hs[hl][swizzled t], hl = local h (0..127)
        #pragma unroll
        for (int i = 0; i < 8; ++i) {
            int t = tg * 8 + i;
            int col = (((t >> 2) ^ (hg & 15)) << 2) | (t & 3);
            #pragma unroll
            for (int jj = 0; jj < 4; ++jj) {
                int hl = hg * 4 + jj;
                sm.b.Hs[hl][col] = acc[i][p * 4 + jj];
            }
        }
        #pragma unroll 1
        for (int c4 = 0; c4 < 4; ++c4) {
            // stage W2 k-chunk [p*128 + c4*32, +32)
            #pragma unroll
            for (int r = 0; r < 2; ++r) {
                int slot = tid + 256 * r;
                int e = slot >> 3, kq = (slot & 7) * 4;
                float4 v = *(const float4*)(w2 + (size_t)e * HID + p * 128 + c4 * 32 + kq);
                int col = (((e >> 2) ^ (kq >> 2)) << 2) | (e & 3);
                sm.b.W2s[kq + 0][col] = v.x;
                sm.b.W2s[kq + 1][col] = v.y;
                sm.b.W2s[kq + 2][col] = v.z;
                sm.b.W2s[kq + 3][col] = v.w;
            }
            __syncthreads();
            #pragma unroll
            for (int m = 0; m < 8; ++m) {
                const float* wb = &sm.b.W2s[0][((eb ^ m) << 2)];
                #pragma unroll
                for (int kk = 0; kk < 4; ++kk) {
                    int k  = m * 4 + kk;
                    int hl = c4 * 32 + k;
                    float4 hv = *(const float4*)&sm.b.Hs[hl][((ta ^ ((hl >> 2) & 15)) << 2)];
                    float4 wv = *(const float4*)(wb + k * 64);
                    float hvv[4] = {hv.x, hv.y, hv.z, hv.w};
                    float wvv[4] = {wv.x, wv.y, wv.z, wv.w};
                    #pragma unroll
                    for (int i = 0; i < 4; ++i)
                        #pragma unroll
                        for (int j = 0; j < 4; ++j)
                            acc2[i][j] = fmaf(hvv[i], wvv[j], acc2[i][j]);
                }
            }
            __syncthreads();
        }
    }

    // logits (+b2) -> Ls
    {
        float4 b2v = *(const float4*)(b2 + eb * 4);
        float bb2[4] = {b2v.x, b2v.y, b2v.z, b2v.w};
        #pragma unroll
        for (int i = 0; i < 4; ++i)
            #pragma unroll
            for (int j = 0; j < 4; ++j)
                sm.Ls[ta * 4 + i][eb * 4 + j] = acc2[i][j] + bb2[j];
    }
    __syncthreads();

    // one lane per token: top-2 scan (strict > keeps lower index on ties,
    // matching jax.lax.top_k), then 2-way softmax.
    if (tid < 64) {
        const int t = tid;
        float m1 = -INFINITY, m2 = -INFINITY;
        int i1 = 0, i2 = 0;
        #pragma unroll 8
        for (int e = 0; e < NE; ++e) {
            float v = sm.Ls[t][e];
            if (v > m1)      { m2 = m1; i2 = i1; m1 = v; i1 = e; }
            else if (v > m2) { m2 = v; i2 = e; }
        }
        float e2  = expf(m2 - m1);           // <= 1, no overflow
        float inv = 1.f / (1.f + e2);
        int gt = t0 + t;
        out[(size_t)gt * 2 + 0] = (float)i1;
        out[(size_t)gt * 2 + 1] = (float)i2;
        out[(size_t)2 * N_TOK + (size_t)gt * 2 + 0] = inv;
        out[(size_t)2 * N_TOK + (size_t)gt * 2 + 1] = e2 * inv;
    }
}

extern "C" void kernel_launch(void* const* d_in, const int* in_sizes, int n_in,
                              void* d_out, int out_size, void* d_ws, size_t ws_size,
                              hipStream_t stream) {
    const float* x  = (const float*)d_in[0];  // [32768,1024]
    const float* w1 = (const float*)d_in[1];  // [256,1024]
    const float* b1 = (const float*)d_in[2];  // [256]
    const float* w2 = (const float*)d_in[3];  // [64,256]
    const float* b2 = (const float*)d_in[4];  // [64]
    float* out = (float*)d_out;               // 131072 floats: idx then gates

    moe_gate_fused<<<N_TOK / 64, 256, 0, stream>>>(x, w1, b1, w2, b2, out);
}

// Round 2
// 371.764 us; speedup vs baseline: 1.4966x; 1.4966x over previous
//
#include <hip/hip_runtime.h>
#include <math.h>

#define N_TOK 32768
#define IN_DIM 1024
#define HID 256
#define NE 64

// Fused gating network:
//   phase A: H[64tok x 256hid] = relu(X W1^T + b1), K=1024 staged in 32-chunks
//   phase B: logits[64 x 64] = H W2^T + b2, H handed off through LDS (no HBM)
//   epilogue: per-token top-2 (ties -> lower index) + 2-way softmax
//
// All LDS tiles are stored [k][col] with an XOR swizzle on the float4-group of
// col, keyed by (k>>2). Both the transpose staging writes and the strided
// fragment reads are conflict-free (verified: SQ_LDS_BANK_CONFLICT 5.3e7 ->
// 9.8e5 in round 1).
//
// NO register prefetch/double-buffer: round 1 showed the 40 staged VGPRs live
// across the barrier push allocation past the 128-reg cap at
// __launch_bounds__(256,2) and spill ~3KB/thread to scratch (WRITE_SIZE
// 435 MB, +140 us). Global->LDS staging is load-then-write per chunk; the
// 2 resident blocks hide each other's load latency (wave-level TLP).
union SMem {
    struct { float Xs[32][64]; float Ws[32][256]; } a;   // 8K + 32K
    struct { float Hs[128][64]; float W2s[32][64]; } b;  // 32K + 8K
    float Ls[64][67];                                    // 17K (bank spread)
};

__global__ __launch_bounds__(256, 2)
void moe_gate_fused(const float* __restrict__ x,  const float* __restrict__ w1,
                    const float* __restrict__ b1, const float* __restrict__ w2,
                    const float* __restrict__ b2, float* __restrict__ out)
{
    __shared__ SMem sm;

    const int tid = threadIdx.x;
    const int t0  = blockIdx.x * 64;
    const int tg  = tid >> 5;       // 0..7  -> tokens tg*8 .. tg*8+7
    const int hg  = tid & 31;       // 0..31 -> hiddens {hg*4..+3, 128+hg*4..+3}

    float acc[8][8];
    #pragma unroll
    for (int i = 0; i < 8; ++i)
        #pragma unroll
        for (int j = 0; j < 8; ++j) acc[i][j] = 0.f;

    // ---------------- phase A: H = relu(X @ W1^T + b1) ----------------
    #pragma unroll 1
    for (int c = 0; c < 32; ++c) {
        const int k0 = c * 32;
        // stage X tile: 64 tok x 32 k = 512 float4, 2 per thread
        #pragma unroll
        for (int r = 0; r < 2; ++r) {
            int slot = tid + 256 * r;
            int t = slot >> 3, kq = (slot & 7) * 4;
            float4 v = *(const float4*)(x + (size_t)(t0 + t) * IN_DIM + k0 + kq);
            int col = (((t >> 2) ^ (kq >> 2)) << 2) | (t & 3);
            sm.a.Xs[kq + 0][col] = v.x;
            sm.a.Xs[kq + 1][col] = v.y;
            sm.a.Xs[kq + 2][col] = v.z;
            sm.a.Xs[kq + 3][col] = v.w;
        }
        // stage W1 tile: 256 h x 32 k = 2048 float4, 8 per thread
        #pragma unroll
        for (int r = 0; r < 8; ++r) {
            int slot = tid + 256 * r;
            int hh = slot >> 3, kq = (slot & 7) * 4;
            float4 v = *(const float4*)(w1 + (size_t)hh * IN_DIM + k0 + kq);
            int col = (((hh >> 2) ^ (kq >> 2)) << 2) | (hh & 3);
            sm.a.Ws[kq + 0][col] = v.x;
            sm.a.Ws[kq + 1][col] = v.y;
            sm.a.Ws[kq + 2][col] = v.z;
            sm.a.Ws[kq + 3][col] = v.w;
        }
        __syncthreads();

        // inner product: swizzle key (k>>2) == m is constant per m-group ->
        // bases hoisted, ds_read offsets become immediates
        #pragma unroll
        for (int m = 0; m < 8; ++m) {
            const float* xb0 = &sm.a.Xs[0][(((tg * 2)     ^ m) << 2)];
            const float* xb1 = &sm.a.Xs[0][(((tg * 2 + 1) ^ m) << 2)];
            const float* wb0 = &sm.a.Ws[0][(( hg ^ m)        << 2)];
            const float* wb1 = &sm.a.Ws[0][((((hg ^ m) + 32)) << 2)];
            #pragma unroll
            for (int kk = 0; kk < 4; ++kk) {
                int k = m * 4 + kk;
                float4 xv0 = *(const float4*)(xb0 + k * 64);
                float4 xv1 = *(const float4*)(xb1 + k * 64);
                float4 wv0 = *(const float4*)(wb0 + k * 256);
                float4 wv1 = *(const float4*)(wb1 + k * 256);
                float xv[8] = {xv0.x, xv0.y, xv0.z, xv0.w, xv1.x, xv1.y, xv1.z, xv1.w};
                float wv[8] = {wv0.x, wv0.y, wv0.z, wv0.w, wv1.x, wv1.y, wv1.z, wv1.w};
                #pragma unroll
                for (int i = 0; i < 8; ++i)
                    #pragma unroll
                    for (int j = 0; j < 8; ++j)
                        acc[i][j] = fmaf(xv[i], wv[j], acc[i][j]);
            }
        }
        __syncthreads();
    }

    // bias + relu (acc[i][j]: j 0..3 -> h=hg*4+j, j 4..7 -> h=128+hg*4+(j-4))
    {
        float4 bb0 = *(const float4*)(b1 + hg * 4);
        float4 bb1 = *(const float4*)(b1 + 128 + hg * 4);
        float bias1[8] = {bb0.x, bb0.y, bb0.z, bb0.w, bb1.x, bb1.y, bb1.z, bb1.w};
        #pragma unroll
        for (int i = 0; i < 8; ++i)
            #pragma unroll
            for (int j = 0; j < 8; ++j)
                acc[i][j] = fmaxf(acc[i][j] + bias1[j], 0.f);
    }

    // ---------------- phase B: logits = H @ W2^T + b2 ----------------
    const int ta = tid >> 4;   // 0..15 -> tokens  ta*4 .. ta*4+3
    const int eb = tid & 15;   // 0..15 -> experts eb*4 .. eb*4+3

    float acc2[4][4];
    #pragma unroll
    for (int i = 0; i < 4; ++i)
        #pragma unroll
        for (int j = 0; j < 4; ++j) acc2[i][j] = 0.f;

    #pragma unroll            // p MUST be compile-time (static acc indexing)
    for (int p = 0; p < 2; ++p) {
        // hand H half-slice to LDS: Hs[hl][swizzled t], hl = local h (0..127)
        #pragma unroll
        for (int i = 0; i < 8; ++i) {
            int t = tg * 8 + i;
            int col = (((t >> 2) ^ (hg & 15)) << 2) | (t & 3);
            #pragma unroll
            for (int jj = 0; jj < 4; ++jj) {
                int hl = hg * 4 + jj;
                sm.b.Hs[hl][col] = acc[i][p * 4 + jj];
            }
        }
        #pragma unroll 1
        for (int c4 = 0; c4 < 4; ++c4) {
            // stage W2 k-chunk [p*128 + c4*32, +32)
            #pragma unroll
            for (int r = 0; r < 2; ++r) {
                int slot = tid + 256 * r;
                int e = slot >> 3, kq = (slot & 7) * 4;
                float4 v = *(const float4*)(w2 + (size_t)e * HID + p * 128 + c4 * 32 + kq);
                int col = (((e >> 2) ^ (kq >> 2)) << 2) | (e & 3);
                sm.b.W2s[kq + 0][col] = v.x;
                sm.b.W2s[kq + 1][col] = v.y;
                sm.b.W2s[kq + 2][col] = v.z;
                sm.b.W2s[kq + 3][col] = v.w;
            }
            __syncthreads();
            #pragma unroll
            for (int m = 0; m < 8; ++m) {
                const float* wb = &sm.b.W2s[0][((eb ^ m) << 2)];
                #pragma unroll
                for (int kk = 0; kk < 4; ++kk) {
                    int k  = m * 4 + kk;
                    int hl = c4 * 32 + k;
                    float4 hv = *(const float4*)&sm.b.Hs[hl][((ta ^ ((hl >> 2) & 15)) << 2)];
                    float4 wv = *(const float4*)(wb + k * 64);
                    float hvv[4] = {hv.x, hv.y, hv.z, hv.w};
                    float wvv[4] = {wv.x, wv.y, wv.z, wv.w};
                    #pragma unroll
                    for (int i = 0; i < 4; ++i)
                        #pragma unroll
                        for (int j = 0; j < 4; ++j)
                            acc2[i][j] = fmaf(hvv[i], wvv[j], acc2[i][j]);
                }
            }
            __syncthreads();
        }
    }

    // logits (+b2) -> Ls
    {
        float4 b2v = *(const float4*)(b2 + eb * 4);
        float bb2[4] = {b2v.x, b2v.y, b2v.z, b2v.w};
        #pragma unroll
        for (int i = 0; i < 4; ++i)
            #pragma unroll
            for (int j = 0; j < 4; ++j)
                sm.Ls[ta * 4 + i][eb * 4 + j] = acc2[i][j] + bb2[j];
    }
    __syncthreads();

    // one lane per token: top-2 scan (strict > keeps lower index on ties,
    // matching jax.lax.top_k), then 2-way softmax.
    if (tid < 64) {
        const int t = tid;
        float m1 = -INFINITY, m2 = -INFINITY;
        int i1 = 0, i2 = 0;
        #pragma unroll 8
        for (int e = 0; e < NE; ++e) {
            float v = sm.Ls[t][e];
            if (v > m1)      { m2 = m1; i2 = i1; m1 = v; i1 = e; }
            else if (v > m2) { m2 = v; i2 = e; }
        }
        float e2  = expf(m2 - m1);           // <= 1, no overflow
        float inv = 1.f / (1.f + e2);
        int gt = t0 + t;
        out[(size_t)gt * 2 + 0] = (float)i1;
        out[(size_t)gt * 2 + 1] = (float)i2;
        out[(size_t)2 * N_TOK + (size_t)gt * 2 + 0] = inv;
        out[(size_t)2 * N_TOK + (size_t)gt * 2 + 1] = e2 * inv;
    }
}

extern "C" void kernel_launch(void* const* d_in, const int* in_sizes, int n_in,
                              void* d_out, int out_size, void* d_ws, size_t ws_size,
                              hipStream_t stream) {
    const float* x  = (const float*)d_in[0];  // [32768,1024]
    const float* w1 = (const float*)d_in[1];  // [256,1024]
    const float* b1 = (const float*)d_in[2];  // [256]
    const float* w2 = (const float*)d_in[3];  // [64,256]
    const float* b2 = (const float*)d_in[4];  // [64]
    float* out = (float*)d_out;               // 131072 floats: idx then gates

    moe_gate_fused<<<N_TOK / 64, 256, 0, stream>>>(x, w1, b1, w2, b2, out);
}